// Round 7
// baseline (764.832 us; speedup 1.0000x reference)
//
#include <hip/hip_runtime.h>
#include <hip/hip_bf16.h>

// EdgeAwareCritic: 3x GATv2 (H=2 heads, HID=128) + FiLM + MLP head, scalar output.
// fp32 inputs; GEMMs in bf16 MFMA. GAT per layer (R19 = R18/R13 two-kernel
// structure with K1 restructured):
//   K1: edge-parallel MFMA logits. xl[src] staged in wave-private LDS (wide fp8
//       gathers); xr[dst] read DIRECTLY from global in the epilogue (CSR-sorted
//       dst -> same L1 lines re-read); We staged in BLOCK LDS (8 KB — the only
//       reliable placement, see R14-R17 notes). LDS 26.6 KB -> 6 blocks/CU.
//       Writes exp(clamp(logit,60)).
//   K2: single-pass per-node softmax-aggregate, 8-deep clamp-and-mask unroll.
// FiLM (R19): ap-GEMM (K=16) fused in — each wave computes its own 32 rows of
//   a = relu(action@apW^T+ap_b) via zero-padded MFMAs into wave-private LDS
//   atile (272 B padded stride), main loop reads A-frags from LDS.
// NOTE (R9): global f32 atomics as edge-accumulators -> ~300 MB HBM write
// amplification on 8-XCD MI355X. Never again.
// NOTE (R12): buffers must not alias (wgt overflow into hbf corrupted silently).
// NOTE (R13): deg/ctr/col zeroed in cvt_many; final scale in gemm_q1's
// last-finishing block.
// NOTE (R14-R17, fused-GAT saga): do NOT carry wide register state (We frags,
// prefetch quads) across fenced loops — the allocator reloads (R14, 50us),
// spills 79 MB (R16, 77us), or spills 486 MB (R17, 197us). Invariant MFMA
// operands go in LDS; loops stay load->use.

typedef __attribute__((ext_vector_type(8))) short bf16x8;   // 8 bf16 = 4 VGPR
typedef __attribute__((ext_vector_type(4))) float f32x4;
typedef __attribute__((ext_vector_type(2))) float f32x2;

#define ZERO8 ((bf16x8){0, 0, 0, 0, 0, 0, 0, 0})

__device__ __forceinline__ unsigned short f2bf(float f) {
    union { float f; unsigned int i; } v; v.f = f;
    unsigned int x = v.i;
    x += 0x7fffu + ((x >> 16) & 1u);   // round-to-nearest-even
    return (unsigned short)(x >> 16);
}
__device__ __forceinline__ unsigned char f2fp8(float f) {
    return (unsigned char)(__builtin_amdgcn_cvt_pk_fp8_f32(f, f, 0, false) & 0xFF);
}
__device__ __forceinline__ void wave_lds_fence() {
    // LDS slices are wave-private: order ds_write -> ds_read within the wave.
    __builtin_amdgcn_wave_barrier();
    asm volatile("s_waitcnt lgkmcnt(0)" ::: "memory");
    __builtin_amdgcn_wave_barrier();
}

// ---------------- multi-tensor fp32 -> bf16 convert (RNE) + zero-init ----
#define MAXCVT 16
struct CvtDescs {
    const float* src[MAXCVT];
    unsigned short* dst[MAXCVT];
    int off4[MAXCVT + 1];   // prefix sums, float4 units
    int cnt;
    int* deg; int ndeg4;
    int* ctr; float* col;
};
__global__ __launch_bounds__(256) void cvt_many_kernel(CvtDescs d) {
    const int tid = blockIdx.x * blockDim.x + threadIdx.x;
    const int stride = gridDim.x * blockDim.x;
    const int total = d.off4[d.cnt];
    for (int i = tid; i < total; i += stride) {
        int e = 0;
        while (d.off4[e + 1] <= i) ++e;     // cnt <= 14, cheap scan
        const int j = i - d.off4[e];
        float4 v = ((const float4*)d.src[e])[j];
        ((ushort4*)d.dst[e])[j] = make_ushort4(f2bf(v.x), f2bf(v.y), f2bf(v.z), f2bf(v.w));
    }
    for (int i = tid; i < d.ndeg4; i += stride)
        ((int4*)d.deg)[i] = make_int4(0, 0, 0, 0);
    if (tid == 0) { *d.ctr = 0; *d.col = 0.f; }
}

// ---------------- CSR build ----------------
__global__ void hist_kernel(const int* __restrict__ dst, int* __restrict__ deg, int n) {
    int i = blockIdx.x * blockDim.x + threadIdx.x;
    if (i < n) atomicAdd(&deg[dst[i]], 1);
}

__global__ __launch_bounds__(1024) void scan_kernel(const int* __restrict__ deg,
                                                    int* __restrict__ rowp,
                                                    int* __restrict__ cur, int n) {
    __shared__ int sums[1024];
    const int t = threadIdx.x;
    const int PER = 20;
    int base = t * PER;
    int local[PER];
    int run = 0;
#pragma unroll
    for (int i = 0; i < PER; ++i) {
        int v = (base + i < n) ? deg[base + i] : 0;
        local[i] = run; run += v;
    }
    sums[t] = run; __syncthreads();
    for (int off = 1; off < 1024; off <<= 1) {
        int v = (t >= off) ? sums[t - off] : 0;
        __syncthreads();
        sums[t] += v;
        __syncthreads();
    }
    int offs = (t > 0) ? sums[t - 1] : 0;
#pragma unroll
    for (int i = 0; i < PER; ++i) {
        int idx = base + i;
        if (idx < n) { int v = offs + local[i]; rowp[idx] = v; cur[idx] = v; }
    }
    if (t == 0) rowp[n] = sums[1023];
}

// scatter: CSR src/dst lists + edge_attr rows -> CSR order bf16 (unpadded, 32 B)
__global__ void scatter_kernel(const int* __restrict__ src, const int* __restrict__ dst,
                               int* __restrict__ cur, const float4* __restrict__ ea,
                               int* __restrict__ csrs, int* __restrict__ csrd,
                               ushort4* __restrict__ eacsr, int n) {
    int i = blockIdx.x * blockDim.x + threadIdx.x;
    if (i < n) {
        int d = dst[i];
        int p = atomicAdd(&cur[d], 1);
        csrs[p] = src[i];
        csrd[p] = d;
        const float4* er = ea + (size_t)i * 4;
        ushort4* eo = eacsr + (size_t)p * 4;
#pragma unroll
        for (int q = 0; q < 4; ++q) {
            float4 v = er[q];
            eo[q] = make_ushort4(f2bf(v.x), f2bf(v.y), f2bf(v.z), f2bf(v.w));
        }
    }
}

// ---------------- bf16 MFMA GEMM: C = A@W^T + bias ----
template <bool RELU, bool SPLIT, bool AF32>
__global__ __launch_bounds__(256) void gemm_mfma_kernel(
    const void* __restrict__ Ap, const unsigned short* __restrict__ W,
    const float* __restrict__ bias0, const float* __restrict__ bias1, int bsplit,
    unsigned short* __restrict__ Cbf, unsigned char* __restrict__ Cf8,
    int M, int N, int K) {
    __shared__ unsigned char ctile[SPLIT ? 128 * 64 : 64];
    const int t = threadIdx.x;
    const int wave = t >> 6, lane = t & 63;
    const int lo = lane & 15, quad = lane >> 4;
    const int m0 = blockIdx.y * 128 + wave * 32;
    const int n0 = blockIdx.x * 64;

    f32x4 acc[2][4];
#pragma unroll
    for (int i = 0; i < 2; ++i)
#pragma unroll
        for (int j = 0; j < 4; ++j) acc[i][j] = (f32x4){0.f, 0.f, 0.f, 0.f};

    for (int k0 = 0; k0 < K; k0 += 32) {
        bf16x8 af[2], bfr[4];
#pragma unroll
        for (int mi = 0; mi < 2; ++mi) {
            const int mb = m0 + mi * 16;
            if (mb >= M) { af[mi] = ZERO8; continue; }
            if (AF32) {
                const float* A = (const float*)Ap;
                float4 a0 = *(const float4*)(A + (size_t)(mb + lo) * K + k0 + quad * 8);
                float4 a1 = *(const float4*)(A + (size_t)(mb + lo) * K + k0 + quad * 8 + 4);
                bf16x8 f;
                f[0] = (short)f2bf(a0.x); f[1] = (short)f2bf(a0.y);
                f[2] = (short)f2bf(a0.z); f[3] = (short)f2bf(a0.w);
                f[4] = (short)f2bf(a1.x); f[5] = (short)f2bf(a1.y);
                f[6] = (short)f2bf(a1.z); f[7] = (short)f2bf(a1.w);
                af[mi] = f;
            } else {
                const unsigned short* A = (const unsigned short*)Ap;
                af[mi] = *(const bf16x8*)(A + (size_t)(mb + lo) * K + k0 + quad * 8);
            }
        }
#pragma unroll
        for (int ni = 0; ni < 4; ++ni)
            bfr[ni] = *(const bf16x8*)(W + (size_t)(n0 + ni * 16 + lo) * K + k0 + quad * 8);
#pragma unroll
        for (int mi = 0; mi < 2; ++mi)
#pragma unroll
            for (int ni = 0; ni < 4; ++ni)
                acc[mi][ni] = __builtin_amdgcn_mfma_f32_16x16x32_bf16(af[mi], bfr[ni], acc[mi][ni], 0, 0, 0);
    }

    float bn[4];
#pragma unroll
    for (int ni = 0; ni < 4; ++ni) {
        const int n = n0 + ni * 16 + lo;
        const float* bp = (n < bsplit) ? bias0 : bias1;
        const int bi = (n < bsplit) ? n : n - bsplit;
        bn[ni] = bp[bi];
    }
    if (SPLIT) {
        // stage fp8 tile in LDS, then cooperative wide stores
#pragma unroll
        for (int mi = 0; mi < 2; ++mi) {
#pragma unroll
            for (int ni = 0; ni < 4; ++ni) {
                const int n = ni * 16 + lo;
#pragma unroll
                for (int r = 0; r < 4; ++r) {
                    float o = acc[mi][ni][r] + bn[ni];
                    if (RELU) o = fmaxf(o, 0.f);
                    ctile[(wave * 32 + mi * 16 + quad * 4 + r) * 64 + n] = f2fp8(o);
                }
            }
        }
        __syncthreads();
        const int row = t >> 1, half = t & 1;
        const int grow = blockIdx.y * 128 + row;
        if (grow < M) {
            const unsigned char* srcp = &ctile[row * 64 + half * 32];
            unsigned char* dstp = Cf8 + (size_t)grow * 512 + n0 + half * 32;
            *(int4*)(dstp) = *(const int4*)(srcp);
            *(int4*)(dstp + 16) = *(const int4*)(srcp + 16);
        }
    } else {
#pragma unroll
        for (int mi = 0; mi < 2; ++mi) {
            const int mb = m0 + mi * 16;
            if (mb >= M) continue;
#pragma unroll
            for (int ni = 0; ni < 4; ++ni) {
                const int n = n0 + ni * 16 + lo;
#pragma unroll
                for (int r = 0; r < 4; ++r) {
                    float o = acc[mi][ni][r] + bn[ni];
                    if (RELU) o = fmaxf(o, 0.f);
                    Cbf[(size_t)(mb + quad * 4 + r) * N + n] = f2bf(o);
                }
            }
        }
    }
}

// ---------------- FiLM gemm + fused ap-GEMM ----
// Phase 0 (per wave, wave-private LDS rows): a = relu(action@apW^T + ap_b)
// for this wave's 32 rows via zero-padded K=16 MFMAs -> atile (bf16, 272 B
// stride). Main loop reads A-frags from atile; then
// hbf = bf16((a@Wg^T+gb)*h + (a@Wb^T+bb)) in place.
__global__ __launch_bounds__(256) void gemm_film_kernel(
    const float* __restrict__ action, const unsigned short* __restrict__ wap,
    const float* __restrict__ apb,
    const unsigned short* __restrict__ Wg, const unsigned short* __restrict__ Wb,
    const float* __restrict__ gb, const float* __restrict__ bb,
    unsigned short* __restrict__ hbf, int M) {
    const int K = 128, N = 128;
    __shared__ __align__(16) unsigned short atile[128][136];   // 34 KB, +8 pad shorts
    const int t = threadIdx.x;
    const int wave = t >> 6, lane = t & 63;
    const int lo = lane & 15, quad = lane >> 4;
    const int m0 = blockIdx.y * 128 + wave * 32;
    const int n0 = blockIdx.x * 64;
    const int r0 = wave * 32;   // atile row base (wave-private slice)

    {   // ---- phase 0: a-rows for this wave (ADIM=16, zero-padded to K=32) ----
        bf16x8 afa[2];
#pragma unroll
        for (int mi = 0; mi < 2; ++mi) {
            const int row = m0 + mi * 16 + lo;
            if (row < M && quad < 2) {
                float4 a0 = *(const float4*)(action + (size_t)row * 16 + quad * 8);
                float4 a1 = *(const float4*)(action + (size_t)row * 16 + quad * 8 + 4);
                bf16x8 f;
                f[0] = (short)f2bf(a0.x); f[1] = (short)f2bf(a0.y);
                f[2] = (short)f2bf(a0.z); f[3] = (short)f2bf(a0.w);
                f[4] = (short)f2bf(a1.x); f[5] = (short)f2bf(a1.y);
                f[6] = (short)f2bf(a1.z); f[7] = (short)f2bf(a1.w);
                afa[mi] = f;
            } else afa[mi] = ZERO8;
        }
#pragma unroll
        for (int nj = 0; nj < 8; ++nj) {
            const bf16x8 bga = (quad < 2)
                ? *(const bf16x8*)(wap + (size_t)(nj * 16 + lo) * 16 + quad * 8) : ZERO8;
            f32x4 aa[2];
#pragma unroll
            for (int mi = 0; mi < 2; ++mi)
                aa[mi] = __builtin_amdgcn_mfma_f32_16x16x32_bf16(
                    afa[mi], bga, (f32x4){0.f, 0.f, 0.f, 0.f}, 0, 0, 0);
            const int ch = nj * 16 + lo;
            const float b = apb[ch];
#pragma unroll
            for (int mi = 0; mi < 2; ++mi)
#pragma unroll
                for (int r = 0; r < 4; ++r)
                    atile[r0 + mi * 16 + quad * 4 + r][ch] =
                        f2bf(fmaxf(aa[mi][r] + b, 0.f));
        }
    }
    wave_lds_fence();   // atile rows are wave-private

    f32x4 accg[2][4], accb[2][4];
#pragma unroll
    for (int i = 0; i < 2; ++i)
#pragma unroll
        for (int j = 0; j < 4; ++j) { accg[i][j] = (f32x4){0.f,0.f,0.f,0.f}; accb[i][j] = accg[i][j]; }

    for (int k0 = 0; k0 < 128; k0 += 32) {
        bf16x8 af[2], bg4[4];
#pragma unroll
        for (int mi = 0; mi < 2; ++mi) {
            const int mb = m0 + mi * 16;
            af[mi] = (mb < M) ? *(const bf16x8*)&atile[r0 + mi * 16 + lo][k0 + quad * 8]
                              : ZERO8;
        }
#pragma unroll
        for (int ni = 0; ni < 4; ++ni)
            bg4[ni] = *(const bf16x8*)(Wg + (size_t)(n0 + ni * 16 + lo) * K + k0 + quad * 8);
#pragma unroll
        for (int mi = 0; mi < 2; ++mi)
#pragma unroll
            for (int ni = 0; ni < 4; ++ni)
                accg[mi][ni] = __builtin_amdgcn_mfma_f32_16x16x32_bf16(af[mi], bg4[ni], accg[mi][ni], 0, 0, 0);
#pragma unroll
        for (int ni = 0; ni < 4; ++ni)
            bg4[ni] = *(const bf16x8*)(Wb + (size_t)(n0 + ni * 16 + lo) * K + k0 + quad * 8);
#pragma unroll
        for (int mi = 0; mi < 2; ++mi)
#pragma unroll
            for (int ni = 0; ni < 4; ++ni)
                accb[mi][ni] = __builtin_amdgcn_mfma_f32_16x16x32_bf16(af[mi], bg4[ni], accb[mi][ni], 0, 0, 0);
    }

#pragma unroll
    for (int mi = 0; mi < 2; ++mi) {
        const int mb = m0 + mi * 16;
        if (mb >= M) continue;
#pragma unroll
        for (int ni = 0; ni < 4; ++ni) {
            const int n = n0 + ni * 16 + lo;
            const float g = gb[n], b = bb[n];
#pragma unroll
            for (int r = 0; r < 4; ++r) {
                const size_t idx = (size_t)(mb + quad * 4 + r) * N + n;
                union { unsigned int i; float f; } hv; hv.i = (unsigned int)hbf[idx] << 16;
                hbf[idx] = f2bf((accg[mi][ni][r] + g) * hv.f + (accb[mi][ni][r] + b));
            }
        }
    }
}

// ---------------- q1 gemm + q2 head + final scale (last-block-done) ----
__global__ __launch_bounds__(256) void gemm_q1_kernel(
    const unsigned short* __restrict__ A, const unsigned short* __restrict__ W,
    const float* __restrict__ q1b, const float* __restrict__ q2w,
    const float* __restrict__ q2b, float* __restrict__ outsum,
    float* __restrict__ outv, int* __restrict__ ctr,
    int M, int nblk, float invn) {
    const int K = 128;
    const int t = threadIdx.x;
    const int wave = t >> 6, lane = t & 63;
    const int lo = lane & 15, quad = lane >> 4;
    const int m0 = blockIdx.y * 128 + wave * 32;
    const int n0 = blockIdx.x * 64;
    __shared__ float red[4];

    f32x4 acc[2][4];
#pragma unroll
    for (int i = 0; i < 2; ++i)
#pragma unroll
        for (int j = 0; j < 4; ++j) acc[i][j] = (f32x4){0.f, 0.f, 0.f, 0.f};

    for (int k0 = 0; k0 < K; k0 += 32) {
        bf16x8 af[2], bfr[4];
#pragma unroll
        for (int mi = 0; mi < 2; ++mi) {
            const int mb = m0 + mi * 16;
            af[mi] = (mb < M) ? *(const bf16x8*)(A + (size_t)(mb + lo) * K + k0 + quad * 8)
                              : ZERO8;
        }
#pragma unroll
        for (int ni = 0; ni < 4; ++ni)
            bfr[ni] = *(const bf16x8*)(W + (size_t)(n0 + ni * 16 + lo) * K + k0 + quad * 8);
#pragma unroll
        for (int mi = 0; mi < 2; ++mi)
#pragma unroll
            for (int ni = 0; ni < 4; ++ni)
                acc[mi][ni] = __builtin_amdgcn_mfma_f32_16x16x32_bf16(af[mi], bfr[ni], acc[mi][ni], 0, 0, 0);
    }

    float partial = 0.f;
#pragma unroll
    for (int mi = 0; mi < 2; ++mi) {
        const int mb = m0 + mi * 16;
        if (mb >= M) continue;
#pragma unroll
        for (int ni = 0; ni < 4; ++ni) {
            const int n = n0 + ni * 16 + lo;
            const float b = q1b[n], w = q2w[n];
#pragma unroll
            for (int r = 0; r < 4; ++r)
                partial += fmaxf(acc[mi][ni][r] + b, 0.f) * w;
        }
    }
    partial += __shfl_xor(partial, 1);  partial += __shfl_xor(partial, 2);
    partial += __shfl_xor(partial, 4);  partial += __shfl_xor(partial, 8);
    partial += __shfl_xor(partial, 16); partial += __shfl_xor(partial, 32);
    if (lane == 0) red[wave] = partial;
    __syncthreads();
    if (t == 0) {
        atomicAdd(outsum, red[0] + red[1] + red[2] + red[3]);
        __threadfence();                                 // device scope
        unsigned int d = atomicAdd((unsigned int*)ctr, 1u);
        if (d == (unsigned int)(nblk - 1)) {
            float s = atomicAdd(outsum, 0.f);            // coherent read-back
            outv[0] = s * invn + q2b[0];
        }
    }
}

// ---------------- GAT K1: MFMA edge logits ----
// xl staged wave-private in LDS (wide fp8 gathers); xr read directly from
// global in epilogue (CSR dst-locality -> L1 hits); We in BLOCK LDS (8 KB).
// LDS 26.6 KB -> 6 blocks/CU. Writes w = exp(min(logit,60)).
#define LSTR 272
__global__ __launch_bounds__(256, 5) void gat_logit_kernel(
    const unsigned char* __restrict__ xf8,
    const int* __restrict__ csrs, const int* __restrict__ csrd,
    const unsigned short* __restrict__ eacsr, const unsigned short* __restrict__ we16,
    const float* __restrict__ att, float* __restrict__ logit, int E) {
    __shared__ float attl[256];
    __shared__ __align__(16) unsigned short wefl[4096];   // We bf16, 8 KB block-shared
    __shared__ __align__(16) unsigned char xls[4][16 * LSTR];
    const int tid = threadIdx.x;
    attl[tid] = att[tid];
    {   // stage We into LDS: 256 threads x 2 int4
        const int4* ws = (const int4*)we16;
        int4* wd = (int4*)wefl;
        wd[tid] = ws[tid];
        wd[tid + 256] = ws[tid + 256];
    }
    const int wave = tid >> 6, lane = tid & 63;
    const int lo = lane & 15, quad = lane >> 4;
    const int sr_row = lane >> 2, c16 = (lane & 3) * 16;
    __syncthreads();   // attl + wefl visibility (one-time)

    const int nb = (E + 15) / 16;
    const int wstride = gridDim.x * 4;
    const int trips = (nb + wstride - 1) / wstride;
    for (int it = 0; it < trips; ++it) {
        const int b = blockIdx.x * 4 + wave + it * wstride;
        if (b >= nb) break;
        const int p0 = b * 16;
        {   // stage xl[src] for 16 edges (clamped)
            const int pr = min(p0 + sr_row, E - 1);
            const int sr = csrs[pr];
            const unsigned char* xs = xf8 + (size_t)sr * 512 + c16;
            unsigned char* ld = &xls[wave][sr_row * LSTR + c16];
#pragma unroll
            for (int j = 0; j < 4; ++j)
                *(int4*)(ld + j * 64) = *(const int4*)(xs + j * 64);
        }
        wave_lds_fence();   // xl writes visible to this wave's lanes
        {
            const bool valid = (p0 + lo) < E;
            const int p = valid ? (p0 + lo) : (E - 1);
            const int dr = csrd[p];
            const unsigned char* xrbase = xf8 + (size_t)dr * 512 + 256;
            const bf16x8 eaf = (quad < 2)
                ? *(const bf16x8*)(eacsr + (size_t)p * 16 + quad * 8) : ZERO8;
            float ph0 = 0.f, ph1 = 0.f;
#pragma unroll
            for (int t = 0; t < 16; ++t) {
                const bf16x8 wf = (quad < 2)
                    ? *(const bf16x8*)&wefl[(t * 16 + lo) * 16 + quad * 8] : ZERO8;
                f32x4 D = __builtin_amdgcn_mfma_f32_16x16x32_bf16(
                    wf, eaf, (f32x4){0.f, 0.f, 0.f, 0.f}, 0, 0, 0);
                const int c0 = t * 16 + quad * 4;
                const unsigned int xlu = *(const unsigned int*)&xls[wave][lo * LSTR + c0];
                const unsigned int xru = *(const unsigned int*)(xrbase + c0);  // L1-hot
                const f32x2 l01 = __builtin_amdgcn_cvt_pk_f32_fp8(xlu, false);
                const f32x2 l23 = __builtin_amdgcn_cvt_pk_f32_fp8(xlu, true);
                const f32x2 r01 = __builtin_amdgcn_cvt_pk_f32_fp8(xru, false);
                const f32x2 r23 = __builtin_amdgcn_cvt_pk_f32_fp8(xru, true);
                const float4 at4 = *(const float4*)&attl[c0];
                float vx = l01.x + r01.x + D[0];
                float vy = l01.y + r01.y + D[1];
                float vz = l23.x + r23.x + D[2];
                float vw = l23.y + r23.y + D[3];
                vx = fmaxf(vx, 0.2f * vx); vy = fmaxf(vy, 0.2f * vy);
                vz = fmaxf(vz, 0.2f * vz); vw = fmaxf(vw, 0.2f * vw);
                const float pt = vx * at4.x + vy * at4.y + vz * at4.z + vw * at4.w;
                if (t < 8) ph0 += pt; else ph1 += pt;
            }
            ph0 += __shfl_xor(ph0, 16); ph0 += __shfl_xor(ph0, 32);
            ph1 += __shfl_xor(ph1, 16); ph1 += __shfl_xor(ph1, 32);
            if (valid) {
                if (quad == 0) logit[p0 + lo] = __expf(fminf(ph0, 60.f));
                else if (quad == 1) logit[(size_t)E + p0 + lo] = __expf(fminf(ph1, 60.f));
            }
        }
        wave_lds_fence();   // xls reads done before next trip's writes
    }
}

// ---------------- GAT K2: single-pass per-node softmax-aggregate (fp8) ----
__global__ __launch_bounds__(256) void gat_na_kernel(
    const unsigned char* __restrict__ xf8,
    const int* __restrict__ rowp, const int* __restrict__ csrs,
    const float* __restrict__ wgt, const float* __restrict__ bias,
    unsigned short* __restrict__ houtb, int nnodes, int E) {
    const int lane = threadIdx.x & 63;
    const int node = blockIdx.x * 4 + (threadIdx.x >> 6);
    if (node >= nnodes) return;
    const int rs = rowp[node], re = rowp[node + 1];
    const int h = lane >> 5;
    const float* lg = wgt + (size_t)h * E;

    float den = 0.f;
    float4 acc = make_float4(0.f, 0.f, 0.f, 0.f);
    for (int i = rs; i < re; i += 8) {
        int s[8]; float w[8]; unsigned int u[8];
#pragma unroll
        for (int k = 0; k < 8; ++k) {
            const int p = min(i + k, re - 1);
            s[k] = csrs[p];
            w[k] = (i + k < re) ? lg[p] : 0.f;
        }
#pragma unroll
        for (int k = 0; k < 8; ++k)
            u[k] = *(const unsigned int*)(xf8 + (size_t)s[k] * 512 + 4 * lane);
#pragma unroll
        for (int k = 0; k < 8; ++k) {
            const f32x2 p01 = __builtin_amdgcn_cvt_pk_f32_fp8(u[k], false);
            const f32x2 p23 = __builtin_amdgcn_cvt_pk_f32_fp8(u[k], true);
            den += w[k];
            acc.x += w[k] * p01.x; acc.y += w[k] * p01.y;
            acc.z += w[k] * p23.x; acc.w += w[k] * p23.y;
        }
    }
    const float inv = (re > rs) ? 1.f / den : 0.f;
    float ox = acc.x * inv, oy = acc.y * inv, oz = acc.z * inv, ow = acc.w * inv;
    // mean over heads: lane l (head0) pairs with lane l^32 (head1, same channels)
    ox += __shfl_xor(ox, 32); oy += __shfl_xor(oy, 32);
    oz += __shfl_xor(oz, 32); ow += __shfl_xor(ow, 32);
    if (lane < 32) {
        float4 bu = *(const float4*)(bias + 4 * lane);
        *(ushort4*)(houtb + (size_t)node * 128 + 4 * lane) = make_ushort4(
            f2bf(fmaxf(0.5f * ox + bu.x, 0.f)), f2bf(fmaxf(0.5f * oy + bu.y, 0.f)),
            f2bf(fmaxf(0.5f * oz + bu.z, 0.f)), f2bf(fmaxf(0.5f * ow + bu.w, 0.f)));
    }
}

extern "C" void kernel_launch(void* const* d_in, const int* in_sizes, int n_in,
                              void* d_out, int out_size, void* d_ws, size_t ws_size,
                              hipStream_t stream) {
    const int N = in_sizes[0] / 128;   // 20000
    const int E = in_sizes[1] / 2;     // 320000

    typedef const float* fp;
    fp x      = (fp)d_in[0];
    const int* ei = (const int*)d_in[1];
    fp ea     = (fp)d_in[2];
    fp action = (fp)d_in[3];
    fp inp_W  = (fp)d_in[4];
    fp inp_b  = (fp)d_in[5];
    fp ap_W = (fp)d_in[27], ap_b = (fp)d_in[28];
    fp g_W  = (fp)d_in[29], g_b  = (fp)d_in[30];
    fp be_W = (fp)d_in[31], be_b = (fp)d_in[32];
    fp q1_W = (fp)d_in[33], q1_b = (fp)d_in[34];
    fp q2_W = (fp)d_in[35], q2_b = (fp)d_in[36];

    char* base = (char*)d_ws;
    size_t off = 0;
    auto alloc = [&](size_t bytes) { char* p = base + off; off = (off + bytes + 255) & ~(size_t)255; return p; };
    unsigned char*  xf8 = (unsigned char*)alloc((size_t)N * 512);       // xl|xr fp8
    float* col  = (float*)alloc(128 * 4);
    int* ctr    = (int*)alloc(256);
    int* deg    = (int*)alloc((size_t)N * 4);
    int* rowp   = (int*)alloc((size_t)(N + 1) * 4);
    int* cur    = (int*)alloc((size_t)N * 4);
    int* csrs   = (int*)alloc((size_t)E * 4);
    int* csrd   = (int*)alloc((size_t)E * 4);
    unsigned short* eacsr = (unsigned short*)alloc((size_t)E * 16 * 2); // ea bf16 CSR order
    float* wgt  = (float*)alloc((size_t)2 * E * 4);                     // exp(logits)
    unsigned short* hbf = (unsigned short*)alloc((size_t)N * 128 * 2);
    unsigned short* wbf = (unsigned short*)alloc((262144 + 3 * 4096 + 2048) * 2);
    (void)ws_size; (void)n_in; (void)out_size;

    unsigned short* winp = wbf;            // 128x128
    unsigned short* w1l  = wbf + 16384;    // [512,128] fused pairs
    unsigned short* w1r  = w1l + 32768;
    unsigned short* w2l  = w1r + 32768;
    unsigned short* w2r  = w2l + 32768;
    unsigned short* wal  = w2r + 32768;
    unsigned short* war  = wal + 32768;
    unsigned short* wg   = war + 32768;    // 128x128
    unsigned short* wbe  = wg + 16384;
    unsigned short* wq1  = wbe + 16384;
    unsigned short* wep1 = wq1 + 16384;    // 3x [256,16] bf16 We (unpadded)
    unsigned short* wep2 = wep1 + 4096;
    unsigned short* wep3 = wep2 + 4096;
    unsigned short* wap  = wep3 + 4096;    // [128,16] bf16 ap_W

    const int* src = ei;
    const int* dst = ei + E;

    CvtDescs cd;
    int ce = 0, acc4 = 0;
    auto addc = [&](const float* s, unsigned short* d, int n) {
        cd.src[ce] = s; cd.dst[ce] = d; cd.off4[ce] = acc4; acc4 += n / 4; ++ce; };
    addc(inp_W, winp, 16384);
    addc((fp)d_in[6],  w1l, 32768); addc((fp)d_in[8],  w1r, 32768);
    addc((fp)d_in[13], w2l, 32768); addc((fp)d_in[15], w2r, 32768);
    addc((fp)d_in[20], wal, 32768); addc((fp)d_in[22], war, 32768);
    addc(g_W, wg, 16384); addc(be_W, wbe, 16384); addc(q1_W, wq1, 16384);
    addc((fp)d_in[10], wep1, 4096); addc((fp)d_in[17], wep2, 4096); addc((fp)d_in[24], wep3, 4096);
    addc(ap_W, wap, 2048);
    cd.off4[ce] = acc4; cd.cnt = ce;
    cd.deg = deg; cd.ndeg4 = (N + 3) / 4;
    cd.ctr = ctr; cd.col = col;
    cvt_many_kernel<<<(acc4 + 255) / 256, 256, 0, stream>>>(cd);

    hist_kernel<<<(E + 255) / 256, 256, 0, stream>>>(dst, deg, E);
    scan_kernel<<<1, 1024, 0, stream>>>(deg, rowp, cur, N);
    scatter_kernel<<<(E + 255) / 256, 256, 0, stream>>>(src, dst, cur, (const float4*)ea,
                                                        csrs, csrd, (ushort4*)eacsr, E);

    const int my = (N + 127) / 128;
    const int nodeg = (N + 3) / 4;

    auto run_gat = [&](const unsigned short* wep, const float* at, const float* bi,
                       unsigned short* hb) {
        gat_logit_kernel<<<2500, 256, 0, stream>>>(xf8, csrs, csrd, eacsr, wep, at, wgt, E);
        gat_na_kernel<<<nodeg, 256, 0, stream>>>(xf8, rowp, csrs, wgt, bi, hb, N, E);
    };

    // h0 = relu(x @ inp_W^T + inp_b) -> bf16 (x read as fp32, cvt in-kernel)
    gemm_mfma_kernel<true, false, true><<<dim3(2, my), 256, 0, stream>>>(
        x, winp, inp_b, inp_b, 128, hbf, nullptr, N, 128, 128);

    // s1
    gemm_mfma_kernel<false, true, false><<<dim3(8, my), 256, 0, stream>>>(
        hbf, w1l, (fp)d_in[7], (fp)d_in[9], 256, nullptr, xf8, N, 512, 128);
    run_gat(wep1, (fp)d_in[11], (fp)d_in[12], hbf);
    // s2
    gemm_mfma_kernel<false, true, false><<<dim3(8, my), 256, 0, stream>>>(
        hbf, w2l, (fp)d_in[14], (fp)d_in[16], 256, nullptr, xf8, N, 512, 128);
    run_gat(wep2, (fp)d_in[18], (fp)d_in[19], hbf);

    // FiLM with fused ap-GEMM (a computed per-wave in LDS)
    gemm_film_kernel<<<dim3(2, my), 256, 0, stream>>>(
        action, wap, ap_b, wg, wbe, g_b, be_b, hbf, N);

    // sa
    gemm_mfma_kernel<false, true, false><<<dim3(8, my), 256, 0, stream>>>(
        hbf, wal, (fp)d_in[21], (fp)d_in[23], 256, nullptr, xf8, N, 512, 128);
    run_gat(wep3, (fp)d_in[25], (fp)d_in[26], hbf);

    // q1 + q2 + mean + final scale fused (last-finishing block writes out)
    gemm_q1_kernel<<<dim3(2, my), 256, 0, stream>>>(
        hbf, wq1, q1_b, q2_W, q2_b, col, (float*)d_out, ctr, N, 2 * my, 1.0f / (float)N);
}

// Round 8
// 422.400 us; speedup vs baseline: 1.8107x; 1.8107x over previous
//
#include <hip/hip_runtime.h>
#include <hip/hip_bf16.h>

// EdgeAwareCritic: 3x GATv2 (H=2 heads, HID=128) + FiLM + MLP head, scalar output.
// fp32 inputs; GEMMs in bf16 MFMA. GAT per layer (R20 = exact R18 revert,
// verified 423.1/425.6 us):
//   K1: edge-parallel MFMA logits; xl/xr fp8 via LDS-staged wide loads
//       (wave-private slices -> wave-level waits, no block barriers).
//       Writes exp(clamp(logit,60)) directly.
//   K2: SINGLE-PASS per-node softmax-aggregate: unnormalized sum(w*x), sum(w),
//       divide once. 8-deep clamp-and-mask unroll (invalid: idx=re-1, w=0 ->
//       numerically exact, no serial tail).
// NOTE (R9): global f32 atomics as edge-accumulators -> ~300 MB HBM write
// amplification on 8-XCD MI355X. Never again.
// NOTE (R12): abf must have a DEDICATED allocation (wgt alias overflowed into
// hbf -> silent corruption).
// NOTE (R13): deg/ctr/col zeroed in cvt_many; final scale in gemm_q1's
// last-finishing block.
// NOTE (R14-R19, the restructure saga): FIVE independent confirmations that
// deviating from this kernel shape triggers allocator pathology:
//   R14: bounds(256,4) caps 128 VGPR -> We reloaded per chunk (50us fused).
//   R15: 48KB LDS double-buffer -> ~1 block/CU (126us).
//   R16: bounds(256,3), We in regs -> SPILLED, 79 MB scratch writes (77us).
//   R17: prefetch quad live across fences -> 486 MB scratch (197us).
//   R19: We in LDS + in-loop global xr reads in K1 -> hoisted live range,
//        412 MB scratch, 146us.
// Conclusion: keep loops load->use, keep wef[16] in regs ONLY in this exact
// K1 shape (bounds(256,4), xls+xrs staging), do not carry other wide state.

typedef __attribute__((ext_vector_type(8))) short bf16x8;   // 8 bf16 = 4 VGPR
typedef __attribute__((ext_vector_type(4))) float f32x4;
typedef __attribute__((ext_vector_type(2))) float f32x2;

#define ZERO8 ((bf16x8){0, 0, 0, 0, 0, 0, 0, 0})

__device__ __forceinline__ unsigned short f2bf(float f) {
    union { float f; unsigned int i; } v; v.f = f;
    unsigned int x = v.i;
    x += 0x7fffu + ((x >> 16) & 1u);   // round-to-nearest-even
    return (unsigned short)(x >> 16);
}
__device__ __forceinline__ unsigned char f2fp8(float f) {
    return (unsigned char)(__builtin_amdgcn_cvt_pk_fp8_f32(f, f, 0, false) & 0xFF);
}
__device__ __forceinline__ void wave_lds_fence() {
    // LDS slices are wave-private: order ds_write -> ds_read within the wave.
    __builtin_amdgcn_wave_barrier();
    asm volatile("s_waitcnt lgkmcnt(0)" ::: "memory");
    __builtin_amdgcn_wave_barrier();
}

// ---------------- multi-tensor fp32 -> bf16 convert (RNE) + zero-init ----
#define MAXCVT 16
struct CvtDescs {
    const float* src[MAXCVT];
    unsigned short* dst[MAXCVT];
    int off4[MAXCVT + 1];   // prefix sums, float4 units
    int cnt;
    int* deg; int ndeg4;
    int* ctr; float* col;
};
__global__ __launch_bounds__(256) void cvt_many_kernel(CvtDescs d) {
    const int tid = blockIdx.x * blockDim.x + threadIdx.x;
    const int stride = gridDim.x * blockDim.x;
    const int total = d.off4[d.cnt];
    for (int i = tid; i < total; i += stride) {
        int e = 0;
        while (d.off4[e + 1] <= i) ++e;     // cnt <= 13, cheap scan
        const int j = i - d.off4[e];
        float4 v = ((const float4*)d.src[e])[j];
        ((ushort4*)d.dst[e])[j] = make_ushort4(f2bf(v.x), f2bf(v.y), f2bf(v.z), f2bf(v.w));
    }
    for (int i = tid; i < d.ndeg4; i += stride)
        ((int4*)d.deg)[i] = make_int4(0, 0, 0, 0);
    if (tid == 0) { *d.ctr = 0; *d.col = 0.f; }
}

// ---------------- CSR build ----------------
__global__ void hist_kernel(const int* __restrict__ dst, int* __restrict__ deg, int n) {
    int i = blockIdx.x * blockDim.x + threadIdx.x;
    if (i < n) atomicAdd(&deg[dst[i]], 1);
}

__global__ __launch_bounds__(1024) void scan_kernel(const int* __restrict__ deg,
                                                    int* __restrict__ rowp,
                                                    int* __restrict__ cur, int n) {
    __shared__ int sums[1024];
    const int t = threadIdx.x;
    const int PER = 20;
    int base = t * PER;
    int local[PER];
    int run = 0;
#pragma unroll
    for (int i = 0; i < PER; ++i) {
        int v = (base + i < n) ? deg[base + i] : 0;
        local[i] = run; run += v;
    }
    sums[t] = run; __syncthreads();
    for (int off = 1; off < 1024; off <<= 1) {
        int v = (t >= off) ? sums[t - off] : 0;
        __syncthreads();
        sums[t] += v;
        __syncthreads();
    }
    int offs = (t > 0) ? sums[t - 1] : 0;
#pragma unroll
    for (int i = 0; i < PER; ++i) {
        int idx = base + i;
        if (idx < n) { int v = offs + local[i]; rowp[idx] = v; cur[idx] = v; }
    }
    if (t == 0) rowp[n] = sums[1023];
}

// scatter: CSR src/dst lists + edge_attr rows -> CSR order bf16 (unpadded, 32 B)
__global__ void scatter_kernel(const int* __restrict__ src, const int* __restrict__ dst,
                               int* __restrict__ cur, const float4* __restrict__ ea,
                               int* __restrict__ csrs, int* __restrict__ csrd,
                               ushort4* __restrict__ eacsr, int n) {
    int i = blockIdx.x * blockDim.x + threadIdx.x;
    if (i < n) {
        int d = dst[i];
        int p = atomicAdd(&cur[d], 1);
        csrs[p] = src[i];
        csrd[p] = d;
        const float4* er = ea + (size_t)i * 4;
        ushort4* eo = eacsr + (size_t)p * 4;
#pragma unroll
        for (int q = 0; q < 4; ++q) {
            float4 v = er[q];
            eo[q] = make_ushort4(f2bf(v.x), f2bf(v.y), f2bf(v.z), f2bf(v.w));
        }
    }
}

// ---------------- bf16 MFMA GEMM: C = A@W^T + bias ----
template <bool RELU, bool SPLIT, bool AF32>
__global__ __launch_bounds__(256) void gemm_mfma_kernel(
    const void* __restrict__ Ap, const unsigned short* __restrict__ W,
    const float* __restrict__ bias0, const float* __restrict__ bias1, int bsplit,
    unsigned short* __restrict__ Cbf, unsigned char* __restrict__ Cf8,
    int M, int N, int K) {
    __shared__ unsigned char ctile[SPLIT ? 128 * 64 : 64];
    const int t = threadIdx.x;
    const int wave = t >> 6, lane = t & 63;
    const int lo = lane & 15, quad = lane >> 4;
    const int m0 = blockIdx.y * 128 + wave * 32;
    const int n0 = blockIdx.x * 64;

    f32x4 acc[2][4];
#pragma unroll
    for (int i = 0; i < 2; ++i)
#pragma unroll
        for (int j = 0; j < 4; ++j) acc[i][j] = (f32x4){0.f, 0.f, 0.f, 0.f};

    for (int k0 = 0; k0 < K; k0 += 32) {
        bf16x8 af[2], bfr[4];
#pragma unroll
        for (int mi = 0; mi < 2; ++mi) {
            const int mb = m0 + mi * 16;
            if (mb >= M) { af[mi] = ZERO8; continue; }
            if (AF32) {
                const float* A = (const float*)Ap;
                float4 a0 = *(const float4*)(A + (size_t)(mb + lo) * K + k0 + quad * 8);
                float4 a1 = *(const float4*)(A + (size_t)(mb + lo) * K + k0 + quad * 8 + 4);
                bf16x8 f;
                f[0] = (short)f2bf(a0.x); f[1] = (short)f2bf(a0.y);
                f[2] = (short)f2bf(a0.z); f[3] = (short)f2bf(a0.w);
                f[4] = (short)f2bf(a1.x); f[5] = (short)f2bf(a1.y);
                f[6] = (short)f2bf(a1.z); f[7] = (short)f2bf(a1.w);
                af[mi] = f;
            } else {
                const unsigned short* A = (const unsigned short*)Ap;
                af[mi] = *(const bf16x8*)(A + (size_t)(mb + lo) * K + k0 + quad * 8);
            }
        }
#pragma unroll
        for (int ni = 0; ni < 4; ++ni)
            bfr[ni] = *(const bf16x8*)(W + (size_t)(n0 + ni * 16 + lo) * K + k0 + quad * 8);
#pragma unroll
        for (int mi = 0; mi < 2; ++mi)
#pragma unroll
            for (int ni = 0; ni < 4; ++ni)
                acc[mi][ni] = __builtin_amdgcn_mfma_f32_16x16x32_bf16(af[mi], bfr[ni], acc[mi][ni], 0, 0, 0);
    }

    float bn[4];
#pragma unroll
    for (int ni = 0; ni < 4; ++ni) {
        const int n = n0 + ni * 16 + lo;
        const float* bp = (n < bsplit) ? bias0 : bias1;
        const int bi = (n < bsplit) ? n : n - bsplit;
        bn[ni] = bp[bi];
    }
    if (SPLIT) {
        // stage fp8 tile in LDS, then cooperative wide stores
#pragma unroll
        for (int mi = 0; mi < 2; ++mi) {
#pragma unroll
            for (int ni = 0; ni < 4; ++ni) {
                const int n = ni * 16 + lo;
#pragma unroll
                for (int r = 0; r < 4; ++r) {
                    float o = acc[mi][ni][r] + bn[ni];
                    if (RELU) o = fmaxf(o, 0.f);
                    ctile[(wave * 32 + mi * 16 + quad * 4 + r) * 64 + n] = f2fp8(o);
                }
            }
        }
        __syncthreads();
        const int row = t >> 1, half = t & 1;
        const int grow = blockIdx.y * 128 + row;
        if (grow < M) {
            const unsigned char* srcp = &ctile[row * 64 + half * 32];
            unsigned char* dstp = Cf8 + (size_t)grow * 512 + n0 + half * 32;
            *(int4*)(dstp) = *(const int4*)(srcp);
            *(int4*)(dstp + 16) = *(const int4*)(srcp + 16);
        }
    } else {
#pragma unroll
        for (int mi = 0; mi < 2; ++mi) {
            const int mb = m0 + mi * 16;
            if (mb >= M) continue;
#pragma unroll
            for (int ni = 0; ni < 4; ++ni) {
                const int n = n0 + ni * 16 + lo;
#pragma unroll
                for (int r = 0; r < 4; ++r) {
                    float o = acc[mi][ni][r] + bn[ni];
                    if (RELU) o = fmaxf(o, 0.f);
                    Cbf[(size_t)(mb + quad * 4 + r) * N + n] = f2bf(o);
                }
            }
        }
    }
}

// ---------------- FiLM gemm: hbf = bf16((a@Wg^T+gb)*h + (a@Wb^T+bb)), in place ----
__global__ __launch_bounds__(256) void gemm_film_kernel(
    const unsigned short* __restrict__ A, const unsigned short* __restrict__ Wg,
    const unsigned short* __restrict__ Wb, const float* __restrict__ gb,
    const float* __restrict__ bb, unsigned short* __restrict__ hbf, int M) {
    const int K = 128, N = 128;
    const int t = threadIdx.x;
    const int wave = t >> 6, lane = t & 63;
    const int lo = lane & 15, quad = lane >> 4;
    const int m0 = blockIdx.y * 128 + wave * 32;
    const int n0 = blockIdx.x * 64;

    f32x4 accg[2][4], accb[2][4];
#pragma unroll
    for (int i = 0; i < 2; ++i)
#pragma unroll
        for (int j = 0; j < 4; ++j) { accg[i][j] = (f32x4){0.f,0.f,0.f,0.f}; accb[i][j] = accg[i][j]; }

    for (int k0 = 0; k0 < 128; k0 += 32) {
        bf16x8 af[2], bg4[4];
#pragma unroll
        for (int mi = 0; mi < 2; ++mi) {
            const int mb = m0 + mi * 16;
            af[mi] = (mb < M) ? *(const bf16x8*)(A + (size_t)(mb + lo) * K + k0 + quad * 8)
                              : ZERO8;
        }
#pragma unroll
        for (int ni = 0; ni < 4; ++ni)
            bg4[ni] = *(const bf16x8*)(Wg + (size_t)(n0 + ni * 16 + lo) * K + k0 + quad * 8);
#pragma unroll
        for (int mi = 0; mi < 2; ++mi)
#pragma unroll
            for (int ni = 0; ni < 4; ++ni)
                accg[mi][ni] = __builtin_amdgcn_mfma_f32_16x16x32_bf16(af[mi], bg4[ni], accg[mi][ni], 0, 0, 0);
#pragma unroll
        for (int ni = 0; ni < 4; ++ni)
            bg4[ni] = *(const bf16x8*)(Wb + (size_t)(n0 + ni * 16 + lo) * K + k0 + quad * 8);
#pragma unroll
        for (int mi = 0; mi < 2; ++mi)
#pragma unroll
            for (int ni = 0; ni < 4; ++ni)
                accb[mi][ni] = __builtin_amdgcn_mfma_f32_16x16x32_bf16(af[mi], bg4[ni], accb[mi][ni], 0, 0, 0);
    }

#pragma unroll
    for (int mi = 0; mi < 2; ++mi) {
        const int mb = m0 + mi * 16;
        if (mb >= M) continue;
#pragma unroll
        for (int ni = 0; ni < 4; ++ni) {
            const int n = n0 + ni * 16 + lo;
            const float g = gb[n], b = bb[n];
#pragma unroll
            for (int r = 0; r < 4; ++r) {
                const size_t idx = (size_t)(mb + quad * 4 + r) * N + n;
                union { unsigned int i; float f; } hv; hv.i = (unsigned int)hbf[idx] << 16;
                hbf[idx] = f2bf((accg[mi][ni][r] + g) * hv.f + (accb[mi][ni][r] + b));
            }
        }
    }
}

// ---------------- q1 gemm + q2 head + final scale (last-block-done) ----
__global__ __launch_bounds__(256) void gemm_q1_kernel(
    const unsigned short* __restrict__ A, const unsigned short* __restrict__ W,
    const float* __restrict__ q1b, const float* __restrict__ q2w,
    const float* __restrict__ q2b, float* __restrict__ outsum,
    float* __restrict__ outv, int* __restrict__ ctr,
    int M, int nblk, float invn) {
    const int K = 128;
    const int t = threadIdx.x;
    const int wave = t >> 6, lane = t & 63;
    const int lo = lane & 15, quad = lane >> 4;
    const int m0 = blockIdx.y * 128 + wave * 32;
    const int n0 = blockIdx.x * 64;
    __shared__ float red[4];

    f32x4 acc[2][4];
#pragma unroll
    for (int i = 0; i < 2; ++i)
#pragma unroll
        for (int j = 0; j < 4; ++j) acc[i][j] = (f32x4){0.f, 0.f, 0.f, 0.f};

    for (int k0 = 0; k0 < K; k0 += 32) {
        bf16x8 af[2], bfr[4];
#pragma unroll
        for (int mi = 0; mi < 2; ++mi) {
            const int mb = m0 + mi * 16;
            af[mi] = (mb < M) ? *(const bf16x8*)(A + (size_t)(mb + lo) * K + k0 + quad * 8)
                              : ZERO8;
        }
#pragma unroll
        for (int ni = 0; ni < 4; ++ni)
            bfr[ni] = *(const bf16x8*)(W + (size_t)(n0 + ni * 16 + lo) * K + k0 + quad * 8);
#pragma unroll
        for (int mi = 0; mi < 2; ++mi)
#pragma unroll
            for (int ni = 0; ni < 4; ++ni)
                acc[mi][ni] = __builtin_amdgcn_mfma_f32_16x16x32_bf16(af[mi], bfr[ni], acc[mi][ni], 0, 0, 0);
    }

    float partial = 0.f;
#pragma unroll
    for (int mi = 0; mi < 2; ++mi) {
        const int mb = m0 + mi * 16;
        if (mb >= M) continue;
#pragma unroll
        for (int ni = 0; ni < 4; ++ni) {
            const int n = n0 + ni * 16 + lo;
            const float b = q1b[n], w = q2w[n];
#pragma unroll
            for (int r = 0; r < 4; ++r)
                partial += fmaxf(acc[mi][ni][r] + b, 0.f) * w;
        }
    }
    partial += __shfl_xor(partial, 1);  partial += __shfl_xor(partial, 2);
    partial += __shfl_xor(partial, 4);  partial += __shfl_xor(partial, 8);
    partial += __shfl_xor(partial, 16); partial += __shfl_xor(partial, 32);
    if (lane == 0) red[wave] = partial;
    __syncthreads();
    if (t == 0) {
        atomicAdd(outsum, red[0] + red[1] + red[2] + red[3]);
        __threadfence();                                 // device scope
        unsigned int d = atomicAdd((unsigned int*)ctr, 1u);
        if (d == (unsigned int)(nblk - 1)) {
            float s = atomicAdd(outsum, 0.f);            // coherent read-back
            outv[0] = s * invn + q2b[0];
        }
    }
}

// ---------------- fp32 vector GEMM (only for ap: K=16) -> bf16 out ----------------
template <int BK, bool RELU>
__global__ __launch_bounds__(256) void gemm_kernel(const float* __restrict__ A,
                                                   const float* __restrict__ W,
                                                   const float* __restrict__ bp,
                                                   unsigned short* __restrict__ Cbf,
                                                   int M, int N, int K) {
    __shared__ float As[BK][68];
    __shared__ float Ws[BK][68];
    const int t = threadIdx.x;
    const int m0 = blockIdx.y * 64;
    const int n0 = blockIdx.x * 64;
    const int tx = t & 15, ty = t >> 4;
    float acc[4][4];
#pragma unroll
    for (int i = 0; i < 4; ++i)
#pragma unroll
        for (int j = 0; j < 4; ++j) acc[i][j] = 0.f;

    for (int k0 = 0; k0 < K; k0 += BK) {
        const int r = t >> 2, cc = (t & 3) * 4;
        const int arow = m0 + r;
        float4 av = (arow < M) ? *(const float4*)(A + (size_t)arow * K + k0 + cc)
                               : make_float4(0.f, 0.f, 0.f, 0.f);
        As[cc + 0][r] = av.x; As[cc + 1][r] = av.y;
        As[cc + 2][r] = av.z; As[cc + 3][r] = av.w;
        float4 wv = *(const float4*)(W + (size_t)(n0 + r) * K + k0 + cc);
        Ws[cc + 0][r] = wv.x; Ws[cc + 1][r] = wv.y;
        Ws[cc + 2][r] = wv.z; Ws[cc + 3][r] = wv.w;
        __syncthreads();
#pragma unroll
        for (int k = 0; k < BK; ++k) {
            float4 a4 = *(const float4*)&As[k][ty * 4];
            float4 b4 = *(const float4*)&Ws[k][tx * 4];
            float a_[4] = {a4.x, a4.y, a4.z, a4.w};
            float b_[4] = {b4.x, b4.y, b4.z, b4.w};
#pragma unroll
            for (int i = 0; i < 4; ++i)
#pragma unroll
                for (int j = 0; j < 4; ++j) acc[i][j] += a_[i] * b_[j];
        }
        __syncthreads();
    }
    float4 bj = *(const float4*)(bp + n0 + tx * 4);
    float bb[4] = {bj.x, bj.y, bj.z, bj.w};
#pragma unroll
    for (int i = 0; i < 4; ++i) {
        int row = m0 + ty * 4 + i;
        if (row < M) {
            float o[4];
#pragma unroll
            for (int j = 0; j < 4; ++j) {
                o[j] = acc[i][j] + bb[j];
                if (RELU) o[j] = fmaxf(o[j], 0.f);
            }
            *(ushort4*)(Cbf + (size_t)row * N + n0 + tx * 4) =
                make_ushort4(f2bf(o[0]), f2bf(o[1]), f2bf(o[2]), f2bf(o[3]));
        }
    }
}

// ---------------- GAT K1: MFMA edge logits, LDS-staged wide fp8 gathers ----
// Wave = 16 CSR positions/batch; LDS slices are WAVE-PRIVATE -> no block
// barriers in the loop, only intra-wave lgkmcnt ordering.
// Writes w = exp(min(logit,60)) so K2 never computes exp.
#define LSTR 272
__global__ __launch_bounds__(256, 4) void gat_logit_kernel(
    const unsigned char* __restrict__ xf8,
    const int* __restrict__ csrs, const int* __restrict__ csrd,
    const unsigned short* __restrict__ eacsr, const unsigned short* __restrict__ we16,
    const float* __restrict__ att, float* __restrict__ logit, int E) {
    __shared__ float attl[256];
    __shared__ __align__(16) unsigned char xls[4][16 * LSTR];
    __shared__ __align__(16) unsigned char xrs[4][16 * LSTR];
    const int tid = threadIdx.x;
    attl[tid] = att[tid];
    const int wave = tid >> 6, lane = tid & 63;
    const int lo = lane & 15, quad = lane >> 4;
    const int sr_row = lane >> 2, c16 = (lane & 3) * 16;

    bf16x8 wef[16];
#pragma unroll
    for (int t = 0; t < 16; ++t)
        wef[t] = (quad < 2) ? *(const bf16x8*)(we16 + (size_t)(t * 16 + lo) * 16 + quad * 8)
                            : ZERO8;
    __syncthreads();   // attl visibility (one-time)

    const int nb = (E + 15) / 16;
    const int wstride = gridDim.x * 4;
    const int trips = (nb + wstride - 1) / wstride;
    for (int it = 0; it < trips; ++it) {
        const int b = blockIdx.x * 4 + wave + it * wstride;
        if (b >= nb) break;
        const int p0 = b * 16;
        {
            const int pr = min(p0 + sr_row, E - 1);
            const int sr = csrs[pr], dr = csrd[pr];
            const unsigned char* xs = xf8 + (size_t)sr * 512 + c16;
            const unsigned char* xrp = xf8 + (size_t)dr * 512 + 256 + c16;
            unsigned char* ld = &xls[wave][sr_row * LSTR + c16];
            unsigned char* rd = &xrs[wave][sr_row * LSTR + c16];
#pragma unroll
            for (int j = 0; j < 4; ++j) {
                *(int4*)(ld + j * 64) = *(const int4*)(xs + j * 64);
                *(int4*)(rd + j * 64) = *(const int4*)(xrp + j * 64);
            }
        }
        wave_lds_fence();   // writes visible to this wave's lanes
        {
            const bool valid = (p0 + lo) < E;
            const int p = valid ? (p0 + lo) : (E - 1);
            const bf16x8 eaf = (quad < 2)
                ? *(const bf16x8*)(eacsr + (size_t)p * 16 + quad * 8) : ZERO8;
            float ph0 = 0.f, ph1 = 0.f;
#pragma unroll
            for (int t = 0; t < 16; ++t) {
                f32x4 D = __builtin_amdgcn_mfma_f32_16x16x32_bf16(
                    wef[t], eaf, (f32x4){0.f, 0.f, 0.f, 0.f}, 0, 0, 0);
                const int c0 = t * 16 + quad * 4;
                const unsigned int xlu = *(const unsigned int*)&xls[wave][lo * LSTR + c0];
                const unsigned int xru = *(const unsigned int*)&xrs[wave][lo * LSTR + c0];
                const f32x2 l01 = __builtin_amdgcn_cvt_pk_f32_fp8(xlu, false);
                const f32x2 l23 = __builtin_amdgcn_cvt_pk_f32_fp8(xlu, true);
                const f32x2 r01 = __builtin_amdgcn_cvt_pk_f32_fp8(xru, false);
                const f32x2 r23 = __builtin_amdgcn_cvt_pk_f32_fp8(xru, true);
                const float4 at4 = *(const float4*)&attl[c0];
                float vx = l01.x + r01.x + D[0];
                float vy = l01.y + r01.y + D[1];
                float vz = l23.x + r23.x + D[2];
                float vw = l23.y + r23.y + D[3];
                vx = fmaxf(vx, 0.2f * vx); vy = fmaxf(vy, 0.2f * vy);
                vz = fmaxf(vz, 0.2f * vz); vw = fmaxf(vw, 0.2f * vw);
                const float pt = vx * at4.x + vy * at4.y + vz * at4.z + vw * at4.w;
                if (t < 8) ph0 += pt; else ph1 += pt;
            }
            ph0 += __shfl_xor(ph0, 16); ph0 += __shfl_xor(ph0, 32);
            ph1 += __shfl_xor(ph1, 16); ph1 += __shfl_xor(ph1, 32);
            if (valid) {
                if (quad == 0) logit[p0 + lo] = __expf(fminf(ph0, 60.f));
                else if (quad == 1) logit[(size_t)E + p0 + lo] = __expf(fminf(ph1, 60.f));
            }
        }
        wave_lds_fence();   // reads done before next trip's writes
    }
}

// ---------------- GAT K2: single-pass per-node softmax-aggregate (fp8) ----
// wgt holds exp(logit) (K1). 8-deep clamp-and-mask unroll: invalid slots use
// idx re-1 with w=0 (exact), so there is NO serial tail loop.
__global__ __launch_bounds__(256) void gat_na_kernel(
    const unsigned char* __restrict__ xf8,
    const int* __restrict__ rowp, const int* __restrict__ csrs,
    const float* __restrict__ wgt, const float* __restrict__ bias,
    unsigned short* __restrict__ houtb, int nnodes, int E) {
    const int lane = threadIdx.x & 63;
    const int node = blockIdx.x * 4 + (threadIdx.x >> 6);
    if (node >= nnodes) return;
    const int rs = rowp[node], re = rowp[node + 1];
    const int h = lane >> 5;
    const float* lg = wgt + (size_t)h * E;

    float den = 0.f;
    float4 acc = make_float4(0.f, 0.f, 0.f, 0.f);
    for (int i = rs; i < re; i += 8) {
        int s[8]; float w[8]; unsigned int u[8];
#pragma unroll
        for (int k = 0; k < 8; ++k) {
            const int p = min(i + k, re - 1);
            s[k] = csrs[p];
            w[k] = (i + k < re) ? lg[p] : 0.f;
        }
#pragma unroll
        for (int k = 0; k < 8; ++k)
            u[k] = *(const unsigned int*)(xf8 + (size_t)s[k] * 512 + 4 * lane);
#pragma unroll
        for (int k = 0; k < 8; ++k) {
            const f32x2 p01 = __builtin_amdgcn_cvt_pk_f32_fp8(u[k], false);
            const f32x2 p23 = __builtin_amdgcn_cvt_pk_f32_fp8(u[k], true);
            den += w[k];
            acc.x += w[k] * p01.x; acc.y += w[k] * p01.y;
            acc.z += w[k] * p23.x; acc.w += w[k] * p23.y;
        }
    }
    const float inv = (re > rs) ? 1.f / den : 0.f;
    float ox = acc.x * inv, oy = acc.y * inv, oz = acc.z * inv, ow = acc.w * inv;
    // mean over heads: lane l (head0) pairs with lane l^32 (head1, same channels)
    ox += __shfl_xor(ox, 32); oy += __shfl_xor(oy, 32);
    oz += __shfl_xor(oz, 32); ow += __shfl_xor(ow, 32);
    if (lane < 32) {
        float4 bu = *(const float4*)(bias + 4 * lane);
        *(ushort4*)(houtb + (size_t)node * 128 + 4 * lane) = make_ushort4(
            f2bf(fmaxf(0.5f * ox + bu.x, 0.f)), f2bf(fmaxf(0.5f * oy + bu.y, 0.f)),
            f2bf(fmaxf(0.5f * oz + bu.z, 0.f)), f2bf(fmaxf(0.5f * ow + bu.w, 0.f)));
    }
}

extern "C" void kernel_launch(void* const* d_in, const int* in_sizes, int n_in,
                              void* d_out, int out_size, void* d_ws, size_t ws_size,
                              hipStream_t stream) {
    const int N = in_sizes[0] / 128;   // 20000
    const int E = in_sizes[1] / 2;     // 320000

    typedef const float* fp;
    fp x      = (fp)d_in[0];
    const int* ei = (const int*)d_in[1];
    fp ea     = (fp)d_in[2];
    fp action = (fp)d_in[3];
    fp inp_W  = (fp)d_in[4];
    fp inp_b  = (fp)d_in[5];
    fp ap_W = (fp)d_in[27], ap_b = (fp)d_in[28];
    fp g_W  = (fp)d_in[29], g_b  = (fp)d_in[30];
    fp be_W = (fp)d_in[31], be_b = (fp)d_in[32];
    fp q1_W = (fp)d_in[33], q1_b = (fp)d_in[34];
    fp q2_W = (fp)d_in[35], q2_b = (fp)d_in[36];

    char* base = (char*)d_ws;
    size_t off = 0;
    auto alloc = [&](size_t bytes) { char* p = base + off; off = (off + bytes + 255) & ~(size_t)255; return p; };
    unsigned char*  xf8 = (unsigned char*)alloc((size_t)N * 512);       // xl|xr fp8
    float* col  = (float*)alloc(128 * 4);
    int* ctr    = (int*)alloc(256);
    int* deg    = (int*)alloc((size_t)N * 4);
    int* rowp   = (int*)alloc((size_t)(N + 1) * 4);
    int* cur    = (int*)alloc((size_t)N * 4);
    int* csrs   = (int*)alloc((size_t)E * 4);
    int* csrd   = (int*)alloc((size_t)E * 4);
    unsigned short* eacsr = (unsigned short*)alloc((size_t)E * 16 * 2); // ea bf16 CSR order
    float* wgt  = (float*)alloc((size_t)2 * E * 4);                     // exp(logits)
    unsigned short* hbf = (unsigned short*)alloc((size_t)N * 128 * 2);
    unsigned short* abf = (unsigned short*)alloc((size_t)N * 128 * 2);  // DEDICATED (R12 bug)
    unsigned short* wbf = (unsigned short*)alloc((262144 + 3 * 4096) * 2);
    (void)ws_size; (void)n_in; (void)out_size;

    unsigned short* winp = wbf;            // 128x128
    unsigned short* w1l  = wbf + 16384;    // [512,128] fused pairs
    unsigned short* w1r  = w1l + 32768;
    unsigned short* w2l  = w1r + 32768;
    unsigned short* w2r  = w2l + 32768;
    unsigned short* wal  = w2r + 32768;
    unsigned short* war  = wal + 32768;
    unsigned short* wg   = war + 32768;    // 128x128
    unsigned short* wbe  = wg + 16384;
    unsigned short* wq1  = wbe + 16384;
    unsigned short* wep1 = wq1 + 16384;    // 3x [256,16] bf16 We (unpadded)
    unsigned short* wep2 = wep1 + 4096;
    unsigned short* wep3 = wep2 + 4096;

    const int* src = ei;
    const int* dst = ei + E;

    CvtDescs cd;
    int ce = 0, acc4 = 0;
    auto addc = [&](const float* s, unsigned short* d, int n) {
        cd.src[ce] = s; cd.dst[ce] = d; cd.off4[ce] = acc4; acc4 += n / 4; ++ce; };
    addc(inp_W, winp, 16384);
    addc((fp)d_in[6],  w1l, 32768); addc((fp)d_in[8],  w1r, 32768);
    addc((fp)d_in[13], w2l, 32768); addc((fp)d_in[15], w2r, 32768);
    addc((fp)d_in[20], wal, 32768); addc((fp)d_in[22], war, 32768);
    addc(g_W, wg, 16384); addc(be_W, wbe, 16384); addc(q1_W, wq1, 16384);
    addc((fp)d_in[10], wep1, 4096); addc((fp)d_in[17], wep2, 4096); addc((fp)d_in[24], wep3, 4096);
    cd.off4[ce] = acc4; cd.cnt = ce;
    cd.deg = deg; cd.ndeg4 = (N + 3) / 4;
    cd.ctr = ctr; cd.col = col;
    cvt_many_kernel<<<(acc4 + 255) / 256, 256, 0, stream>>>(cd);

    hist_kernel<<<(E + 255) / 256, 256, 0, stream>>>(dst, deg, E);
    scan_kernel<<<1, 1024, 0, stream>>>(deg, rowp, cur, N);
    scatter_kernel<<<(E + 255) / 256, 256, 0, stream>>>(src, dst, cur, (const float4*)ea,
                                                        csrs, csrd, (ushort4*)eacsr, E);

    const int my = (N + 127) / 128;
    const int nodeg = (N + 3) / 4;

    auto run_gat = [&](const unsigned short* wep, const float* at, const float* bi,
                       unsigned short* hb) {
        gat_logit_kernel<<<2500, 256, 0, stream>>>(xf8, csrs, csrd, eacsr, wep, at, wgt, E);
        gat_na_kernel<<<nodeg, 256, 0, stream>>>(xf8, rowp, csrs, wgt, bi, hb, N, E);
    };

    // h0 = relu(x @ inp_W^T + inp_b) -> bf16 (x read as fp32, cvt in-kernel)
    gemm_mfma_kernel<true, false, true><<<dim3(2, my), 256, 0, stream>>>(
        x, winp, inp_b, inp_b, 128, hbf, nullptr, N, 128, 128);

    // s1
    gemm_mfma_kernel<false, true, false><<<dim3(8, my), 256, 0, stream>>>(
        hbf, w1l, (fp)d_in[7], (fp)d_in[9], 256, nullptr, xf8, N, 512, 128);
    run_gat(wep1, (fp)d_in[11], (fp)d_in[12], hbf);
    // s2
    gemm_mfma_kernel<false, true, false><<<dim3(8, my), 256, 0, stream>>>(
        hbf, w2l, (fp)d_in[14], (fp)d_in[16], 256, nullptr, xf8, N, 512, 128);
    run_gat(wep2, (fp)d_in[18], (fp)d_in[19], hbf);

    // FiLM: a = relu(action@ap^T+ap_b) -> abf (dedicated); gamma/beta gemm in-place on hbf
    gemm_kernel<16, true><<<dim3(2, (N + 63) / 64), 256, 0, stream>>>(
        action, ap_W, ap_b, abf, N, 128, 16);
    gemm_film_kernel<<<dim3(2, my), 256, 0, stream>>>(abf, wg, wbe, g_b, be_b, hbf, N);

    // sa
    gemm_mfma_kernel<false, true, false><<<dim3(8, my), 256, 0, stream>>>(
        hbf, wal, (fp)d_in[21], (fp)d_in[23], 256, nullptr, xf8, N, 512, 128);
    run_gat(wep3, (fp)d_in[25], (fp)d_in[26], hbf);

    // q1 + q2 + mean + final scale fused (last-finishing block writes out)
    gemm_q1_kernel<<<dim3(2, my), 256, 0, stream>>>(
        hbf, wq1, q1_b, q2_W, q2_b, col, (float*)d_out, ctr, N, 2 * my, 1.0f / (float)N);
}